// Round 13
// baseline (164.368 us; speedup 1.0000x reference)
//
#include <hip/hip_runtime.h>
#include <hip/hip_bf16.h>
#include <hip/hip_fp16.h>
#include <math.h>

#define N_NODES 100000
#define N_EDGES 1600000
#define HEADS 8
#define HC 128
#define LOG2E 1.44269504f

#define DPB 64
#define NB 1563
#define NBP (NB + 1)
#define NCH 512
#define EPC (N_EDGES / NCH)
#define CAPS 1664
#define WSTR (CAPS + 4)
#define CAPH 832                  // per-half x-stage cap (mean ~592, +10 sigma)
#define NA 196                    // amat-role blocks (196*512 >= 100000)

// ============ K1: fused a-matrix node pass + counting sort ===================
// r9/r12 champion form unchanged: LDS-staged entries, coalesced offs/stg
// writes (r10: scattered -8us), separate aligned arrays (r11: packing lost).
__global__ __launch_bounds__(512) void k_prep(
    const float* __restrict__ x, const float* __restrict__ W,
    const float* __restrict__ att_s, const float* __restrict__ att_d,
    const int* __restrict__ ei,
    unsigned short* __restrict__ a_srcb, float* __restrict__ a_dst,
    uint4* __restrict__ x2b,
    int* __restrict__ offs, unsigned* __restrict__ stg) {
    __shared__ int smem[2048 + EPC];
    __shared__ int ws8[8];
    int t = threadIdx.x;
    if (blockIdx.x >= NCH) {
        float* sM = (float*)smem;
        if (t < 256) {
            int k = t >> 4, h2 = t & 15;
            const float* av = (h2 < 8) ? att_s : att_d;
            int h = h2 & 7;
            float s = 0.f;
#pragma unroll
            for (int c = 0; c < 16; ++c)
                s = fmaf(W[k * HC + h * 16 + c], av[h * 16 + c], s);
            sM[k * 16 + h2] = s * LOG2E;
        }
        __syncthreads();
        int node = (blockIdx.x - NCH) * 512 + t;
        if (node < N_NODES) {
            const float4* xr = (const float4*)(x + node * 16);
            float4 x0 = xr[0], x1 = xr[1], x2 = xr[2], x3 = xr[3];
            float xv[16] = {x0.x, x0.y, x0.z, x0.w, x1.x, x1.y, x1.z, x1.w,
                            x2.x, x2.y, x2.z, x2.w, x3.x, x3.y, x3.z, x3.w};
            union { uint4 u[2]; __hip_bfloat162 b[8]; } px;
#pragma unroll
            for (int k = 0; k < 8; ++k)
                px.b[k] = __float22bfloat162_rn(float2{xv[2 * k], xv[2 * k + 1]});
            x2b[node * 2] = px.u[0];
            x2b[node * 2 + 1] = px.u[1];
            float oo[16];
#pragma unroll
            for (int h2 = 0; h2 < 16; ++h2) {
                float o = 0.f;
#pragma unroll
                for (int k = 0; k < 16; ++k) o = fmaf(xv[k], sM[k * 16 + h2], o);
                oo[h2] = o;
            }
            union { uint4 u; unsigned short s[8]; } pb;
#pragma unroll
            for (int h = 0; h < 8; ++h)
                pb.s[h] = __bfloat16_as_ushort(__float2bfloat16(oo[h]));
            *(uint4*)(a_srcb + (size_t)node * 8) = pb.u;
            float4 d0 = {oo[8], oo[9], oo[10], oo[11]};
            float4 d1 = {oo[12], oo[13], oo[14], oo[15]};
            *(float4*)(a_dst + (size_t)node * 8) = d0;
            *(float4*)(a_dst + (size_t)node * 8 + 4) = d1;
        }
    } else {
        int* hist = smem;
        unsigned* entries = (unsigned*)(smem + 2048);
        int c = blockIdx.x;
        hist[t] = 0; hist[t + 512] = 0; hist[t + 1024] = 0; hist[t + 1536] = 0;
        __syncthreads();
        int beg = c * EPC, end = beg + EPC;
        for (int e = beg + t; e < end; e += 512)
            atomicAdd(&hist[ei[N_EDGES + e] >> 6], 1);
        __syncthreads();
        int i0 = 4 * t;
        int v0 = hist[i0], v1 = hist[i0 + 1], v2 = hist[i0 + 2], v3 = hist[i0 + 3];
        int s1 = v0 + v1, s2 = s1 + v2, T = s2 + v3;
        int lane = t & 63, wv = t >> 6;
        int inc = T;
#pragma unroll
        for (int off = 1; off < 64; off <<= 1) {
            int y = __shfl_up(inc, off);
            if (lane >= off) inc += y;
        }
        if (lane == 63) ws8[wv] = inc;
        __syncthreads();
        int wbase = 0;
        for (int k = 0; k < wv; ++k) wbase += ws8[k];
        int e0 = wbase + inc - T;
        hist[i0] = e0; hist[i0 + 1] = e0 + v0;
        hist[i0 + 2] = e0 + s1; hist[i0 + 3] = e0 + s2;
        __syncthreads();
        int row = c * NBP;
        for (int b = t; b < NB; b += 512) offs[row + b] = hist[b];
        if (t == 0) offs[row + NB] = EPC;
        __syncthreads();
        for (int e = beg + t; e < end; e += 512) {
            int src = ei[e], dst = ei[N_EDGES + e];
            int pos = atomicAdd(&hist[dst >> 6], 1);
            entries[pos] = ((unsigned)(dst & 63) << 17) | (unsigned)src;
        }
        __syncthreads();
        unsigned* so = stg + beg;
        for (int i = t; i < EPC; i += 512) so[i] = entries[i];
    }
}

// ============ K2: sort -> fused placement+weights -> LDS-staged gather =======
// NEW vs r12: phase 6 split into two dest-halves; per half, bulk-stage the
// half's x rows into LDS (coalesced LDS writes, 512-thread MLP amortizes the
// random-L2 latency once), then the hot loop reads xst at LDS latency with a
// conflict-free broadcast pattern (8 lanes share each 16B; 4 groups x 32B =
// one full bank row). cstage read also disappears from the hot loop. estg
// aliases the xst buffer (dead after phase 5). LDS ~71KB -> 2 blocks/CU.
__global__ __launch_bounds__(512) void k_gather(
    const __hip_bfloat162* __restrict__ x2b,
    const unsigned short* __restrict__ a_srcb, const float* __restrict__ W,
    const float* __restrict__ a_dst,
    const int* __restrict__ offs, const unsigned* __restrict__ stg,
    const float* __restrict__ bias, const float* __restrict__ fc_w,
    const float* __restrict__ fc_b, float* __restrict__ out) {
    __shared__ __align__(16) uint4 xst[CAPH * 2];        // 26.6KB; estg aliases
    __shared__ __align__(16) unsigned short wst[8 * WSTR];
    __shared__ __align__(16) int sbuf[CAPS];   // o0_s|myb_s (ph1-2) / cstage
    __shared__ __align__(16) float sW[16 * HC];
    __shared__ __align__(16) float sad[8 * DPB];
    __shared__ int hist[DPB];
    __shared__ int bs[DPB + 1];
    __shared__ int ws8[8];
    unsigned* estg = (unsigned*)xst;   // [CAPS], dead after phase 5
    int* cstage = sbuf;
    int* o0_s = sbuf;              // [512], dead after phase 2
    int* myb_s = sbuf + 512;       // [513], dead after phase 2
    int b = blockIdx.x, t = threadIdx.x;
    int d0 = b * DPB;
    for (int i = t; i < 16 * HC; i += 512) {
        int c = i & 127, k = i >> 7;
        int blk = c >> 3;
        int sb = blk ^ ((blk >> 2) & 3);
        sW[k * HC + sb * 8 + (c & 7)] = W[i];
    }
    sad[t] = (d0 * 8 + t < N_NODES * 8) ? a_dst[(size_t)d0 * 8 + t] : 0.f;
    // phase 1: segment starts/lengths (transposed offs read; no k_tr kernel)
    int lane = t & 63, wv = t >> 6;
    {
        int o0 = offs[t * NBP + b];
        int len = offs[t * NBP + b + 1] - o0;
        o0_s[t] = o0;
        int inc = len;
#pragma unroll
        for (int off = 1; off < 64; off <<= 1) {
            int y = __shfl_up(inc, off);
            if (lane >= off) inc += y;
        }
        if (lane == 63) ws8[wv] = inc;
        __syncthreads();
        int wbase = 0;
        for (int k = 0; k < wv; ++k) wbase += ws8[k];
        myb_s[t] = wbase + inc - len;
        if (t == 511) myb_s[NCH] = wbase + inc;
    }
    if (t < DPB) hist[t] = (d0 + t < N_NODES) ? 1 : 0;
    __syncthreads();
    int tot = myb_s[NCH];
    // phase 2 (+3 merged): coalesced copy + dest histogram in one pass
    for (int i = t; i < tot; i += 512) {
        int lo = 0, hi = NCH - 1;
#pragma unroll
        for (int s = 0; s < 9; ++s) {
            int mid = (lo + hi + 1) >> 1;
            if (myb_s[mid] <= i) lo = mid; else hi = mid - 1;
        }
        unsigned u = stg[lo * EPC + o0_s[lo] + (i - myb_s[lo])];
        estg[i] = u;
        atomicAdd(&hist[u >> 17], 1);
    }
    __syncthreads();
    // phase 4: pad to x4, 64-scan, selfs (with weights) + dummy zero-weights
    if (t < 64) {
        int gd = d0 + t;
        bool val = gd < N_NODES;
        int len = hist[t];
        int plen = (len + 3) & ~3;
        int iv = plen;
#pragma unroll
        for (int off = 1; off < 64; off <<= 1) {
            int y = __shfl_up(iv, off);
            if (t >= off) iv += y;
        }
        int excl = iv - plen;
        bs[t] = excl;
        if (t == 63) bs[64] = iv;
        hist[t] = excl + (val ? 1 : 0);
        for (int k = len; k < plen; ++k) {
            cstage[excl + k] = 0;          // dummy -> node 0, weight 0
#pragma unroll
            for (int h = 0; h < 8; ++h) wst[h * WSTR + excl + k] = 0;
        }
        if (val) {
            cstage[excl] = gd;
            union { uint4 v; __hip_bfloat162 b2[4]; } pa;
            pa.v = *(const uint4*)(a_srcb + (size_t)gd * 8);
            const float* adp = sad + t * 8;
            float4 ad0 = *(const float4*)(adp);
            float4 ad1 = *(const float4*)(adp + 4);
            float2 s01 = __bfloat1622float2(pa.b2[0]);
            float2 s23 = __bfloat1622float2(pa.b2[1]);
            float2 s45 = __bfloat1622float2(pa.b2[2]);
            float2 s67 = __bfloat1622float2(pa.b2[3]);
            float e[8] = {s01.x + ad0.x, s01.y + ad0.y, s23.x + ad0.z,
                          s23.y + ad0.w, s45.x + ad1.x, s45.y + ad1.y,
                          s67.x + ad1.z, s67.y + ad1.w};
#pragma unroll
            for (int h = 0; h < 8; ++h) {
                float eh = fmaxf(e[h], 0.2f * e[h]);
                wst[h * WSTR + excl] =
                    __half_as_ushort(__float2half(exp2f(eh)));
            }
        }
    }
    __syncthreads();
    // phase 5 (fused): place edges dest-sorted + weights at placement time
    for (int i = t; i < tot; i += 512) {
        unsigned u = estg[i];
        int pos = atomicAdd(&hist[u >> 17], 1);
        int s = (int)(u & 0x1FFFF);
        int dl = (int)(u >> 17);
        cstage[pos] = s;
        union { uint4 v; __hip_bfloat162 b2[4]; } pa;
        pa.v = *(const uint4*)(a_srcb + (size_t)s * 8);
        const float* adp = sad + dl * 8;
        float4 ad0 = *(const float4*)(adp);
        float4 ad1 = *(const float4*)(adp + 4);
        float2 s01 = __bfloat1622float2(pa.b2[0]);
        float2 s23 = __bfloat1622float2(pa.b2[1]);
        float2 s45 = __bfloat1622float2(pa.b2[2]);
        float2 s67 = __bfloat1622float2(pa.b2[3]);
        float e[8] = {s01.x + ad0.x, s01.y + ad0.y, s23.x + ad0.z, s23.y + ad0.w,
                      s45.x + ad1.x, s45.y + ad1.y, s67.x + ad1.z, s67.y + ad1.w};
#pragma unroll
        for (int h = 0; h < 8; ++h) {
            float eh = fmaxf(e[h], 0.2f * e[h]);
            wst[h * WSTR + pos] = __half_as_ushort(__float2half(exp2f(eh)));
        }
    }
    __syncthreads();
    // phase 6: two dest-halves; stage x to LDS, then 16-lane/8-ch gather
    int q = t & 15, g = t >> 4;
    int head = q >> 1, i8 = q & 1;
    int c0 = head * 16 + i8 * 8;
    int blk0 = c0 >> 3;
    int sw0 = (blk0 ^ ((blk0 >> 2) & 3)) * 8;
    const unsigned short* wrow = wst + head * WSTR;
    const uint4* x4 = (const uint4*)x2b;
    float bb[8], fwv[8][5], fbv[5];
#pragma unroll
    for (int m = 0; m < 8; ++m) bb[m] = bias[c0 + m];
#pragma unroll
    for (int m = 0; m < 8; ++m)
#pragma unroll
        for (int jj = 0; jj < 5; ++jj) fwv[m][jj] = fc_w[(c0 + m) * 5 + jj];
#pragma unroll
    for (int jj = 0; jj < 5; ++jj) fbv[jj] = fc_b[jj];
    for (int h = 0; h < 2; ++h) {
        int hs = bs[h * 32], he = bs[h * 32 + 32];
        // stage this half's x rows (coalesced LDS writes, bulk-parallel MLP)
        for (int i = hs + t; i < he; i += 512) {
            int s = cstage[i];
            int kk = (i - hs) * 2;
            xst[kk] = x4[2 * s];
            xst[kk + 1] = x4[2 * s + 1];
        }
        __syncthreads();
        int l = h * 32 + g;
        int gd = d0 + l;
        if (gd < N_NODES) {
            int beg = bs[l], end = bs[l + 1];
            float A[8] = {0.f, 0.f, 0.f, 0.f, 0.f, 0.f, 0.f, 0.f};
            float wsum = 0.f;
            auto acc = [&](const uint4& xv, float w) {
                union { uint4 v; __hip_bfloat162 b2[4]; } xx; xx.v = xv;
                float2 f0 = __bfloat1622float2(xx.b2[0]);
                float2 f1 = __bfloat1622float2(xx.b2[1]);
                float2 f2 = __bfloat1622float2(xx.b2[2]);
                float2 f3 = __bfloat1622float2(xx.b2[3]);
                A[0] = fmaf(w, f0.x, A[0]); A[1] = fmaf(w, f0.y, A[1]);
                A[2] = fmaf(w, f1.x, A[2]); A[3] = fmaf(w, f1.y, A[3]);
                A[4] = fmaf(w, f2.x, A[4]); A[5] = fmaf(w, f2.y, A[5]);
                A[6] = fmaf(w, f3.x, A[6]); A[7] = fmaf(w, f3.y, A[7]);
            };
            for (int j = beg; j < end; j += 4) {
                uint2 wu = *(const uint2*)(wrow + j);
                union { uint2 u2; __half2 h2[2]; } wq; wq.u2 = wu;
                float2 w01 = __half22float2(wq.h2[0]);
                float2 w23 = __half22float2(wq.h2[1]);
                int k0 = (j - hs) * 2 + i8;
                uint4 xv0 = xst[k0];
                uint4 xv1 = xst[k0 + 2];
                uint4 xv2 = xst[k0 + 4];
                uint4 xv3 = xst[k0 + 6];
                acc(xv0, w01.x); acc(xv1, w01.y);
                acc(xv2, w23.x); acc(xv3, w23.y);
                wsum += (w01.x + w01.y) + (w23.x + w23.y);
            }
            float inv = 1.f / (wsum + 1e-16f);
#pragma unroll
            for (int m = 0; m < 8; ++m) A[m] *= inv;
            float ov[8] = {0.f, 0.f, 0.f, 0.f, 0.f, 0.f, 0.f, 0.f};
#pragma unroll
            for (int m = 0; m < 8; ++m) {
                float a = A[m];
                float ap = __shfl_xor(A[m], 1);
                const float* w0r = sW + (i8 * 8 + m) * HC + sw0;
                const float* w1r = sW + ((1 - i8) * 8 + m) * HC + sw0;
#pragma unroll
                for (int o = 0; o < 8; ++o) ov[o] = fmaf(a, w0r[o], ov[o]);
#pragma unroll
                for (int o = 0; o < 8; ++o) ov[o] = fmaf(ap, w1r[o], ov[o]);
            }
#pragma unroll
            for (int m = 0; m < 8; ++m) ov[m] = fmaxf(ov[m] + bb[m], 0.f);
            float p[5];
#pragma unroll
            for (int jj = 0; jj < 5; ++jj) {
                float sacc = 0.f;
#pragma unroll
                for (int m = 0; m < 8; ++m) sacc = fmaf(ov[m], fwv[m][jj], sacc);
                p[jj] = sacc;
            }
#pragma unroll
            for (int off = 8; off >= 1; off >>= 1)
#pragma unroll
                for (int jj = 0; jj < 5; ++jj) p[jj] += __shfl_xor(p[jj], off);
            if (q == 0) {
                float lg[5], mx = -1e30f;
#pragma unroll
                for (int jj = 0; jj < 5; ++jj) {
                    lg[jj] = p[jj] + fbv[jj];
                    mx = fmaxf(mx, lg[jj]);
                }
                float sum = 0.f;
#pragma unroll
                for (int jj = 0; jj < 5; ++jj) sum += __expf(lg[jj] - mx);
                float ls = mx + __logf(sum);
#pragma unroll
                for (int jj = 0; jj < 5; ++jj) out[gd * 5 + jj] = lg[jj] - ls;
            }
        }
        __syncthreads();
    }
}

extern "C" void kernel_launch(void* const* d_in, const int* in_sizes, int n_in,
                              void* d_out, int out_size, void* d_ws, size_t ws_size,
                              hipStream_t stream) {
    const float* x     = (const float*)d_in[0];
    const int*   ei    = (const int*)d_in[1];
    const float* W     = (const float*)d_in[2];
    const float* att_s = (const float*)d_in[3];
    const float* att_d = (const float*)d_in[4];
    const float* bias  = (const float*)d_in[5];
    const float* fc_w  = (const float*)d_in[6];
    const float* fc_b  = (const float*)d_in[7];
    float* out = (float*)d_out;

    char* ws = (char*)d_ws;
    size_t off = 0;
    auto carve = [&](size_t bytes) {
        void* p = ws + off;
        off = (off + bytes + 255) & ~(size_t)255;
        return p;
    };
    unsigned short* a_srcb = (unsigned short*)carve((size_t)N_NODES * HEADS * 2);
    float*    a_dst = (float*)   carve((size_t)N_NODES * HEADS * 4);
    uint4*    x2b   = (uint4*)   carve((size_t)N_NODES * 32);
    int*      offs  = (int*)     carve((size_t)NCH * NBP * 4);
    unsigned* stg   = (unsigned*)carve((size_t)N_EDGES * 4);

    k_prep<<<NCH + NA, 512, 0, stream>>>(x, W, att_s, att_d, ei,
                                         a_srcb, a_dst, x2b, offs, stg);
    k_gather<<<NB, 512, 0, stream>>>((const __hip_bfloat162*)x2b, a_srcb, W,
                                     a_dst, offs, stg, bias, fc_w, fc_b, out);
}

// Round 14
// 162.079 us; speedup vs baseline: 1.0141x; 1.0141x over previous
//
#include <hip/hip_runtime.h>
#include <hip/hip_bf16.h>
#include <hip/hip_fp16.h>
#include <math.h>

#define N_NODES 100000
#define N_EDGES 1600000
#define HEADS 8
#define HC 128
#define LOG2E 1.44269504f

#define DPB 64
#define NB 1563
#define NBP (NB + 1)
#define NCH 512
#define EPC (N_EDGES / NCH)
#define CAPS 1664
#define WSTR (CAPS + 4)
#define NA 196                    // amat-role blocks (196*512 >= 100000)

// ============ K1: fused a-matrix node pass + counting sort ===================
// Champion (r9, 162.7us total). Ledger of refuted variants:
//  r8: csort/amat split  -7us (co-scheduling lost). r10: scattered offsT-write
//  + global placement -6us (write decoalescing). r2: dst-stash -5us (live-range
//  bloat). r11: 48B packed node records -1.5us (line straddle).
__global__ __launch_bounds__(512) void k_prep(
    const float* __restrict__ x, const float* __restrict__ W,
    const float* __restrict__ att_s, const float* __restrict__ att_d,
    const int* __restrict__ ei,
    unsigned short* __restrict__ a_srcb, float* __restrict__ a_dst,
    uint4* __restrict__ x2b,
    int* __restrict__ offs, unsigned* __restrict__ stg) {
    __shared__ int smem[2048 + EPC];
    __shared__ int ws8[8];
    int t = threadIdx.x;
    if (blockIdx.x >= NCH) {
        float* sM = (float*)smem;
        if (t < 256) {
            int k = t >> 4, h2 = t & 15;
            const float* av = (h2 < 8) ? att_s : att_d;
            int h = h2 & 7;
            float s = 0.f;
#pragma unroll
            for (int c = 0; c < 16; ++c)
                s = fmaf(W[k * HC + h * 16 + c], av[h * 16 + c], s);
            sM[k * 16 + h2] = s * LOG2E;
        }
        __syncthreads();
        int node = (blockIdx.x - NCH) * 512 + t;
        if (node < N_NODES) {
            const float4* xr = (const float4*)(x + node * 16);
            float4 x0 = xr[0], x1 = xr[1], x2 = xr[2], x3 = xr[3];
            float xv[16] = {x0.x, x0.y, x0.z, x0.w, x1.x, x1.y, x1.z, x1.w,
                            x2.x, x2.y, x2.z, x2.w, x3.x, x3.y, x3.z, x3.w};
            union { uint4 u[2]; __hip_bfloat162 b[8]; } px;
#pragma unroll
            for (int k = 0; k < 8; ++k)
                px.b[k] = __float22bfloat162_rn(float2{xv[2 * k], xv[2 * k + 1]});
            x2b[node * 2] = px.u[0];
            x2b[node * 2 + 1] = px.u[1];
            float oo[16];
#pragma unroll
            for (int h2 = 0; h2 < 16; ++h2) {
                float o = 0.f;
#pragma unroll
                for (int k = 0; k < 16; ++k) o = fmaf(xv[k], sM[k * 16 + h2], o);
                oo[h2] = o;
            }
            union { uint4 u; unsigned short s[8]; } pb;
#pragma unroll
            for (int h = 0; h < 8; ++h)
                pb.s[h] = __bfloat16_as_ushort(__float2bfloat16(oo[h]));
            *(uint4*)(a_srcb + (size_t)node * 8) = pb.u;
            float4 d0 = {oo[8], oo[9], oo[10], oo[11]};
            float4 d1 = {oo[12], oo[13], oo[14], oo[15]};
            *(float4*)(a_dst + (size_t)node * 8) = d0;
            *(float4*)(a_dst + (size_t)node * 8 + 4) = d1;
        }
    } else {
        int* hist = smem;
        unsigned* entries = (unsigned*)(smem + 2048);
        int c = blockIdx.x;
        hist[t] = 0; hist[t + 512] = 0; hist[t + 1024] = 0; hist[t + 1536] = 0;
        __syncthreads();
        int beg = c * EPC, end = beg + EPC;
        for (int e = beg + t; e < end; e += 512)
            atomicAdd(&hist[ei[N_EDGES + e] >> 6], 1);
        __syncthreads();
        int i0 = 4 * t;
        int v0 = hist[i0], v1 = hist[i0 + 1], v2 = hist[i0 + 2], v3 = hist[i0 + 3];
        int s1 = v0 + v1, s2 = s1 + v2, T = s2 + v3;
        int lane = t & 63, wv = t >> 6;
        int inc = T;
#pragma unroll
        for (int off = 1; off < 64; off <<= 1) {
            int y = __shfl_up(inc, off);
            if (lane >= off) inc += y;
        }
        if (lane == 63) ws8[wv] = inc;
        __syncthreads();
        int wbase = 0;
        for (int k = 0; k < wv; ++k) wbase += ws8[k];
        int e0 = wbase + inc - T;
        hist[i0] = e0; hist[i0 + 1] = e0 + v0;
        hist[i0 + 2] = e0 + s1; hist[i0 + 3] = e0 + s2;
        __syncthreads();
        int row = c * NBP;
        for (int b = t; b < NB; b += 512) offs[row + b] = hist[b];
        if (t == 0) offs[row + NB] = EPC;
        __syncthreads();
        for (int e = beg + t; e < end; e += 512) {
            int src = ei[e], dst = ei[N_EDGES + e];
            int pos = atomicAdd(&hist[dst >> 6], 1);
            entries[pos] = ((unsigned)(dst & 63) << 17) | (unsigned)src;
        }
        __syncthreads();
        unsigned* so = stg + beg;
        for (int i = t; i < EPC; i += 512) so[i] = entries[i];
    }
}

// ============ K2: sort -> f16 weights -> wide gather =========================
// Champion (r9): transposed offs read (k_tr eliminated, +7us net), merged
// phase 2+3 histogram, separate 6a weight pass (r12 fusion: ±0, more LDS),
// f16 wst, swizzled sW, 16-lane/8-channel gather. Refuted: serpentine (r6
// -6), prefetch (r2 VGPR cliff -26), (512,8) bounds (r3 spill -86), W-from-
// global (r4 -11), LDS x-staging (r13 -2).
__global__ __launch_bounds__(512) void k_gather(
    const __hip_bfloat162* __restrict__ x2b,
    const unsigned short* __restrict__ a_srcb, const float* __restrict__ W,
    const float* __restrict__ a_dst,
    const int* __restrict__ offs, const unsigned* __restrict__ stg,
    const float* __restrict__ bias, const float* __restrict__ fc_w,
    const float* __restrict__ fc_b, float* __restrict__ out) {
    __shared__ __align__(16) unsigned buf0[(8 * WSTR) / 2]; // estage | wst
    __shared__ __align__(16) int sbuf[CAPS];   // o0_s|myb_s (ph1-2) / cstage
    __shared__ __align__(16) float sW[16 * HC];
    __shared__ __align__(16) float sad[8 * DPB + 8];
    __shared__ int hist[DPB];
    __shared__ int bs[DPB + 1];
    __shared__ int ws8[8];
    unsigned* estage = buf0;
    unsigned short* wst = (unsigned short*)buf0;
    int* cstage = sbuf;
    int* o0_s = sbuf;              // [512], dead after phase 2
    int* myb_s = sbuf + 512;       // [513], dead after phase 2
    int b = blockIdx.x, t = threadIdx.x;
    int d0 = b * DPB;
    for (int i = t; i < 16 * HC; i += 512) {
        int c = i & 127, k = i >> 7;
        int blk = c >> 3;
        int sb = blk ^ ((blk >> 2) & 3);
        sW[k * HC + sb * 8 + (c & 7)] = W[i];
    }
    sad[t] = (d0 * 8 + t < N_NODES * 8) ? a_dst[(size_t)d0 * 8 + t] : 0.f;
    if (t < 8) sad[8 * DPB + t] = -100000.f;    // dummy-slot row -> w = 0
    // phase 1: segment starts/lengths (transposed offs read; no k_tr kernel)
    int lane = t & 63, wv = t >> 6;
    {
        int o0 = offs[t * NBP + b];
        int len = offs[t * NBP + b + 1] - o0;
        o0_s[t] = o0;
        int inc = len;
#pragma unroll
        for (int off = 1; off < 64; off <<= 1) {
            int y = __shfl_up(inc, off);
            if (lane >= off) inc += y;
        }
        if (lane == 63) ws8[wv] = inc;
        __syncthreads();
        int wbase = 0;
        for (int k = 0; k < wv; ++k) wbase += ws8[k];
        myb_s[t] = wbase + inc - len;
        if (t == 511) myb_s[NCH] = wbase + inc;
    }
    if (t < DPB) hist[t] = (d0 + t < N_NODES) ? 1 : 0;
    __syncthreads();
    int tot = myb_s[NCH];
    // phase 2 (+3 merged): coalesced copy + dest histogram in one pass
    for (int i = t; i < tot; i += 512) {
        int lo = 0, hi = NCH - 1;
#pragma unroll
        for (int s = 0; s < 9; ++s) {
            int mid = (lo + hi + 1) >> 1;
            if (myb_s[mid] <= i) lo = mid; else hi = mid - 1;
        }
        unsigned u = stg[lo * EPC + o0_s[lo] + (i - myb_s[lo])];
        estage[i] = u;
        atomicAdd(&hist[u >> 17], 1);
    }
    __syncthreads();
    // phase 4: pad segments to x4, 64-scan, place self loops + dummies
    if (t < 64) {
        int gd = d0 + t;
        bool val = gd < N_NODES;
        int len = hist[t];
        int plen = (len + 3) & ~3;
        int iv = plen;
#pragma unroll
        for (int off = 1; off < 64; off <<= 1) {
            int y = __shfl_up(iv, off);
            if (t >= off) iv += y;
        }
        int excl = iv - plen;
        bs[t] = excl;
        if (t == 63) bs[64] = iv;
        if (val) cstage[excl] = (t << 17) | gd;
        hist[t] = excl + (val ? 1 : 0);
        for (int k = len; k < plen; ++k) cstage[excl + k] = (64 << 17);
    }
    __syncthreads();
    // phase 5: place edges dest-sorted
    for (int i = t; i < tot; i += 512) {
        unsigned u = estage[i];
        int pos = atomicAdd(&hist[u >> 17], 1);
        cstage[pos] = (int)u;
    }
    __syncthreads();
    // phase 6a: edge-parallel weight compute -> f16 wst[head][edge]
    int ctot = bs[DPB];
    for (int i = t; i < ctot; i += 512) {
        unsigned u = (unsigned)cstage[i];
        int s = (int)(u & 0x1FFFF);
        int dl = (int)(u >> 17);
        union { uint4 v; __hip_bfloat162 b2[4]; } pa;
        pa.v = *(const uint4*)(a_srcb + (size_t)s * 8);
        const float* adp = sad + dl * 8;
        float4 ad0 = *(const float4*)(adp);
        float4 ad1 = *(const float4*)(adp + 4);
        float2 s01 = __bfloat1622float2(pa.b2[0]);
        float2 s23 = __bfloat1622float2(pa.b2[1]);
        float2 s45 = __bfloat1622float2(pa.b2[2]);
        float2 s67 = __bfloat1622float2(pa.b2[3]);
        float e[8] = {s01.x + ad0.x, s01.y + ad0.y, s23.x + ad0.z, s23.y + ad0.w,
                      s45.x + ad1.x, s45.y + ad1.y, s67.x + ad1.z, s67.y + ad1.w};
#pragma unroll
        for (int h = 0; h < 8; ++h) {
            float eh = fmaxf(e[h], 0.2f * e[h]);
            float w = exp2f(eh);
            wst[h * WSTR + i] = __half_as_ushort(__float2half(w));
        }
    }
    __syncthreads();
    // phase 6b: 16-lane groups, 8 channels/lane, 4-edge unrolled gather
    int q = t & 15, g = t >> 4;
    int head = q >> 1, i8 = q & 1;
    int c0 = head * 16 + i8 * 8;
    int blk0 = c0 >> 3;
    int sw0 = (blk0 ^ ((blk0 >> 2) & 3)) * 8;
    const unsigned short* wrow = wst + head * WSTR;
    int xofs = i8 * 16;
    const char* xb = (const char*)x2b;
    float bb[8], fwv[8][5], fbv[5];
#pragma unroll
    for (int m = 0; m < 8; ++m) bb[m] = bias[c0 + m];
#pragma unroll
    for (int m = 0; m < 8; ++m)
#pragma unroll
        for (int jj = 0; jj < 5; ++jj) fwv[m][jj] = fc_w[(c0 + m) * 5 + jj];
#pragma unroll
    for (int jj = 0; jj < 5; ++jj) fbv[jj] = fc_b[jj];
    for (int l4 = 0; l4 < 2; ++l4) {
        int l = g * 2 + l4;
        int gd = d0 + l;
        if (gd >= N_NODES) break;
        int beg = bs[l], end = bs[l + 1];
        float A[8] = {0.f, 0.f, 0.f, 0.f, 0.f, 0.f, 0.f, 0.f};
        float wsum = 0.f;
        auto acc = [&](const uint4& xv, float w) {
            union { uint4 v; __hip_bfloat162 b2[4]; } xx; xx.v = xv;
            float2 f0 = __bfloat1622float2(xx.b2[0]);
            float2 f1 = __bfloat1622float2(xx.b2[1]);
            float2 f2 = __bfloat1622float2(xx.b2[2]);
            float2 f3 = __bfloat1622float2(xx.b2[3]);
            A[0] = fmaf(w, f0.x, A[0]); A[1] = fmaf(w, f0.y, A[1]);
            A[2] = fmaf(w, f1.x, A[2]); A[3] = fmaf(w, f1.y, A[3]);
            A[4] = fmaf(w, f2.x, A[4]); A[5] = fmaf(w, f2.y, A[5]);
            A[6] = fmaf(w, f3.x, A[6]); A[7] = fmaf(w, f3.y, A[7]);
        };
        for (int j = beg; j < end; j += 4) {
            int4 cs = *(const int4*)(cstage + j);
            uint2 wu = *(const uint2*)(wrow + j);
            union { uint2 u2; __half2 h2[2]; } wq; wq.u2 = wu;
            float2 w01 = __half22float2(wq.h2[0]);
            float2 w23 = __half22float2(wq.h2[1]);
            int s0 = cs.x & 0x1FFFF, s1 = cs.y & 0x1FFFF;
            int s2 = cs.z & 0x1FFFF, s3 = cs.w & 0x1FFFF;
            uint4 xv0 = *(const uint4*)(xb + ((s0 << 5) + xofs));
            uint4 xv1 = *(const uint4*)(xb + ((s1 << 5) + xofs));
            uint4 xv2 = *(const uint4*)(xb + ((s2 << 5) + xofs));
            uint4 xv3 = *(const uint4*)(xb + ((s3 << 5) + xofs));
            acc(xv0, w01.x); acc(xv1, w01.y);
            acc(xv2, w23.x); acc(xv3, w23.y);
            wsum += (w01.x + w01.y) + (w23.x + w23.y);
        }
        float inv = 1.f / (wsum + 1e-16f);
#pragma unroll
        for (int m = 0; m < 8; ++m) A[m] *= inv;
        // epilogue: full 16 x-channels via 1 shfl_xor; swizzled sW columns
        float ov[8] = {0.f, 0.f, 0.f, 0.f, 0.f, 0.f, 0.f, 0.f};
#pragma unroll
        for (int m = 0; m < 8; ++m) {
            float a = A[m];
            float ap = __shfl_xor(A[m], 1);
            const float* w0r = sW + (i8 * 8 + m) * HC + sw0;
            const float* w1r = sW + ((1 - i8) * 8 + m) * HC + sw0;
#pragma unroll
            for (int o = 0; o < 8; ++o) ov[o] = fmaf(a, w0r[o], ov[o]);
#pragma unroll
            for (int o = 0; o < 8; ++o) ov[o] = fmaf(ap, w1r[o], ov[o]);
        }
#pragma unroll
        for (int m = 0; m < 8; ++m) ov[m] = fmaxf(ov[m] + bb[m], 0.f);
        float p[5];
#pragma unroll
        for (int jj = 0; jj < 5; ++jj) {
            float sacc = 0.f;
#pragma unroll
            for (int m = 0; m < 8; ++m) sacc = fmaf(ov[m], fwv[m][jj], sacc);
            p[jj] = sacc;
        }
#pragma unroll
        for (int off = 8; off >= 1; off >>= 1)
#pragma unroll
            for (int jj = 0; jj < 5; ++jj) p[jj] += __shfl_xor(p[jj], off);
        if (q == 0) {
            float lg[5], mx = -1e30f;
#pragma unroll
            for (int jj = 0; jj < 5; ++jj) {
                lg[jj] = p[jj] + fbv[jj];
                mx = fmaxf(mx, lg[jj]);
            }
            float sum = 0.f;
#pragma unroll
            for (int jj = 0; jj < 5; ++jj) sum += __expf(lg[jj] - mx);
            float ls = mx + __logf(sum);
#pragma unroll
            for (int jj = 0; jj < 5; ++jj) out[gd * 5 + jj] = lg[jj] - ls;
        }
    }
}

extern "C" void kernel_launch(void* const* d_in, const int* in_sizes, int n_in,
                              void* d_out, int out_size, void* d_ws, size_t ws_size,
                              hipStream_t stream) {
    const float* x     = (const float*)d_in[0];
    const int*   ei    = (const int*)d_in[1];
    const float* W     = (const float*)d_in[2];
    const float* att_s = (const float*)d_in[3];
    const float* att_d = (const float*)d_in[4];
    const float* bias  = (const float*)d_in[5];
    const float* fc_w  = (const float*)d_in[6];
    const float* fc_b  = (const float*)d_in[7];
    float* out = (float*)d_out;

    char* ws = (char*)d_ws;
    size_t off = 0;
    auto carve = [&](size_t bytes) {
        void* p = ws + off;
        off = (off + bytes + 255) & ~(size_t)255;
        return p;
    };
    unsigned short* a_srcb = (unsigned short*)carve((size_t)N_NODES * HEADS * 2);
    float*    a_dst = (float*)   carve((size_t)N_NODES * HEADS * 4);
    uint4*    x2b   = (uint4*)   carve((size_t)N_NODES * 32);
    int*      offs  = (int*)     carve((size_t)NCH * NBP * 4);
    unsigned* stg   = (unsigned*)carve((size_t)N_EDGES * 4);

    k_prep<<<NCH + NA, 512, 0, stream>>>(x, W, att_s, att_d, ei,
                                         a_srcb, a_dst, x2b, offs, stg);
    k_gather<<<NB, 512, 0, stream>>>((const __hip_bfloat162*)x2b, a_srcb, W,
                                     a_dst, offs, stg, bias, fc_w, fc_b, out);
}